// Round 7
// baseline (341.257 us; speedup 1.0000x reference)
//
#include <hip/hip_runtime.h>
#include <math.h>

typedef unsigned short ushort_t;

// ---------------------------------------------------------------------------
// DPP-based add: x += x[lane ^ pattern], pure VALU.
// 0xB1 quad_perm xor1 | 0x4E quad_perm xor2 | 0x141 row_half_mirror (xor7)
// 0x140 row_mirror (xor15)
// ---------------------------------------------------------------------------
template<int CTRL>
__device__ __forceinline__ float dpp_addf(float x)
{
    int y = __builtin_amdgcn_update_dpp(0, __float_as_int(x), CTRL, 0xf, 0xf, true);
    return x + __int_as_float(y);
}

template<int LPE>
__device__ __forceinline__ float group_reduce(float p)
{
    p = dpp_addf<0xB1>(p);                      // xor 1
    p = dpp_addf<0x4E>(p);                      // xor 2
    if constexpr (LPE >= 8)  p = dpp_addf<0x141>(p); // xor 7
    if constexpr (LPE >= 16) p = dpp_addf<0x140>(p); // xor 15
    return p;
}

__device__ __forceinline__ ushort_t f2bf(float f)
{
    unsigned u = __float_as_uint(f);
    return (ushort_t)((u + 0x7fffu + ((u >> 16) & 1u)) >> 16);   // RNE
}

struct F8 { float v[8]; };

// ---------------------------------------------------------------------------
// Graph prep kernels
// ---------------------------------------------------------------------------

__global__ __launch_bounds__(256)
void deg_kernel(const int* __restrict__ ei, int* __restrict__ cnt,
                int* __restrict__ rank, int E)
{
    int e = blockIdx.x * 256 + threadIdx.x;
    if (e >= E) return;
    rank[e] = atomicAdd(&cnt[ei[E + e]], 1);
}

__global__ __launch_bounds__(256)
void scan_p1(const int* __restrict__ cnt, int* __restrict__ bsums, int n)
{
    __shared__ int s[256];
    const int tid = threadIdx.x;
    int gi = blockIdx.x * 256 + tid;
    s[tid] = (gi < n) ? cnt[gi] : 0;
    __syncthreads();
    #pragma unroll
    for (int off = 128; off >= 1; off >>= 1) {
        if (tid < off) s[tid] += s[tid + off];
        __syncthreads();
    }
    if (tid == 0) bsums[blockIdx.x] = s[0];
}

__global__ __launch_bounds__(256)
void scan_p2(int* __restrict__ bsums, int nb)
{
    __shared__ int s[256];
    const int tid = threadIdx.x;
    int v = (tid < nb) ? bsums[tid] : 0;
    s[tid] = v;
    __syncthreads();
    #pragma unroll
    for (int off = 1; off < 256; off <<= 1) {
        int t = (tid >= off) ? s[tid - off] : 0;
        __syncthreads();
        s[tid] += t;
        __syncthreads();
    }
    if (tid < nb) bsums[tid] = s[tid] - v;      // exclusive
}

__global__ __launch_bounds__(256)
void scan_p3(const int* __restrict__ cnt, const int* __restrict__ bsums,
             int* __restrict__ row_off, int n)
{
    __shared__ int s[256];
    const int tid = threadIdx.x;
    int gi = blockIdx.x * 256 + tid;
    int c = (gi < n) ? cnt[gi] : 0;
    s[tid] = c;
    __syncthreads();
    #pragma unroll
    for (int off = 1; off < 256; off <<= 1) {
        int t = (tid >= off) ? s[tid - off] : 0;
        __syncthreads();
        s[tid] += t;
        __syncthreads();
    }
    if (gi < n) {
        int excl = bsums[blockIdx.x] + s[tid] - c;
        row_off[gi] = excl;
        if (gi == n - 1) row_off[n] = excl + c;   // == E
    }
}

// atomic-free scatter: slot position = row_off[dst] + rank
__global__ __launch_bounds__(256)
void scatter_kernel(const int* __restrict__ ei, const float* __restrict__ ew,
                    const int* __restrict__ row_off, const int* __restrict__ rank,
                    int2* __restrict__ slot, int E)
{
    int e = blockIdx.x * 256 + threadIdx.x;
    if (e >= E) return;
    int d = ei[E + e];
    slot[row_off[d] + rank[e]] = make_int2(ei[e], __float_as_int(ew[e]));
}

// ---------------------------------------------------------------------------
// Fused linear: xl (cols [0,N/2), -> bf16) and xr (cols [N/2,N), fp32).
// XOR-quad-swizzled LDS, 128x128 tile, K chunks of 32.
// ---------------------------------------------------------------------------
template<int N, int K>
__global__ __launch_bounds__(256, 2)
void gemm_xw(const float* __restrict__ X,
             const float* __restrict__ Wa, const float* __restrict__ Wb,
             const float* __restrict__ ba, const float* __restrict__ bb,
             ushort_t* __restrict__ OutA, float* __restrict__ OutB, int M)
{
    constexpr int NJ = N / 16;
    __shared__ float sA[128 * 32];
    __shared__ float sB[N * 32];
    const int tid = threadIdx.x;
    const int m0  = blockIdx.x * 128;
    const int rg  = tid >> 4;
    const int cg  = tid & 15;

    float acc[8][NJ];
    #pragma unroll
    for (int i = 0; i < 8; ++i)
        #pragma unroll
        for (int j = 0; j < NJ; ++j) acc[i][j] = 0.f;

    const int sr = tid >> 3;
    const int kq = tid & 7;
    const int aswz = (kq ^ (sr & 7)) << 2;

    for (int kb = 0; kb < K; kb += 32) {
        #pragma unroll
        for (int p = 0; p < 4; ++p) {
            int r = sr + 32 * p;
            float4 v = make_float4(0.f, 0.f, 0.f, 0.f);
            int gr = m0 + r;
            if (gr < M) v = *(const float4*)(X + (size_t)gr * K + kb + kq * 4);
            *(float4*)&sA[r * 32 + aswz] = v;
        }
        #pragma unroll
        for (int p = 0; p < N / 32; ++p) {
            int r = sr + 32 * p;
            const float* Wsrc = (r < N / 2) ? (Wa + (size_t)r * K)
                                            : (Wb + (size_t)(r - N / 2) * K);
            float4 v = *(const float4*)(Wsrc + kb + kq * 4);
            *(float4*)&sB[r * 32 + aswz] = v;
        }
        __syncthreads();

        #pragma unroll
        for (int q = 0; q < 8; ++q) {
            float4 a4[8], b4[NJ];
            const int sa_off = (q ^ (rg & 7)) << 2;
            const int sb_off = (q ^ (cg & 7)) << 2;
            #pragma unroll
            for (int i = 0; i < 8; ++i)
                a4[i] = *(const float4*)&sA[(rg + 16 * i) * 32 + sa_off];
            #pragma unroll
            for (int j = 0; j < NJ; ++j)
                b4[j] = *(const float4*)&sB[(cg + 16 * j) * 32 + sb_off];
            #pragma unroll
            for (int i = 0; i < 8; ++i)
                #pragma unroll
                for (int j = 0; j < NJ; ++j) {
                    acc[i][j] += a4[i].x * b4[j].x;
                    acc[i][j] += a4[i].y * b4[j].y;
                    acc[i][j] += a4[i].z * b4[j].z;
                    acc[i][j] += a4[i].w * b4[j].w;
                }
        }
        __syncthreads();
    }

    #pragma unroll
    for (int i = 0; i < 8; ++i) {
        int row = m0 + rg + 16 * i;
        if (row >= M) continue;
        #pragma unroll
        for (int j = 0; j < NJ; ++j) {
            int col = cg + 16 * j;
            if (col < N / 2) {
                OutA[(size_t)row * (N / 2) + col] = f2bf(acc[i][j] + ba[col]);
            } else {
                OutB[(size_t)row * (N / 2) + col - N / 2] = acc[i][j] + bb[col - N / 2];
            }
        }
    }
}

// ---------------------------------------------------------------------------
// Per-node GATv2 attention + aggregation, bf16-gather layout.
// xl stored bf16: a D=64 row = 128B = ONE cacheline. Each lane owns 8 dims
// (16B = dwordx4); LPE = D/8 lanes per edge; SG = 64/LPE edges per gather
// instruction (8 for D=64, 16 for D=32) -> 2x fewer cachelines AND 2x fewer
// vmem instructions per edge than the fp32-float4 version.
// ACT: 0 = ELU (layer 1), 1 = softplus + 1e-4 (layer 2)
// ---------------------------------------------------------------------------
template<int D, int ACT>
__global__ __launch_bounds__(256)
void edge_attn(const ushort_t* __restrict__ xl, const float* __restrict__ xr,
               const float* __restrict__ We, const float* __restrict__ att,
               const float* __restrict__ bias,
               const int* __restrict__ row_off, const int2* __restrict__ slot,
               float* __restrict__ out, int n)
{
    constexpr int LPE = D / 8;                 // lanes per edge
    constexpr int SG  = 64 / LPE;              // edges per round
    const int lane = threadIdx.x & 63;
    const int wid  = threadIdx.x >> 6;
    const int t    = lane % LPE;               // owns dims 8t..8t+7
    const int g    = lane / LPE;               // edge slot within round
    const int node = blockIdx.x * 4 + wid;
    if (node >= n) return;

    float We8[8], att8[8], bias8[8], xr8[8];
    *(float4*)&We8[0]   = *(const float4*)(We   + 8 * t);
    *(float4*)&We8[4]   = *(const float4*)(We   + 8 * t + 4);
    *(float4*)&att8[0]  = *(const float4*)(att  + 8 * t);
    *(float4*)&att8[4]  = *(const float4*)(att  + 8 * t + 4);
    *(float4*)&bias8[0] = *(const float4*)(bias + 8 * t);
    *(float4*)&bias8[4] = *(const float4*)(bias + 8 * t + 4);
    *(float4*)&xr8[0]   = *(const float4*)(xr + (size_t)node * D + 8 * t);
    *(float4*)&xr8[4]   = *(const float4*)(xr + (size_t)node * D + 8 * t + 4);

    const int start = row_off[node];
    const int end   = row_off[node + 1];

    float denom = 0.f, wsum = 0.f;
    float acc[8];
    #pragma unroll
    for (int k = 0; k < 8; ++k) acc[k] = 0.f;

    auto gather = [&](int src) -> F8 {
        uint4 d = *(const uint4*)(xl + (size_t)src * D + 8 * t);
        F8 r;
        r.v[0] = __uint_as_float(d.x << 16); r.v[1] = __uint_as_float(d.x & 0xffff0000u);
        r.v[2] = __uint_as_float(d.y << 16); r.v[3] = __uint_as_float(d.y & 0xffff0000u);
        r.v[4] = __uint_as_float(d.z << 16); r.v[5] = __uint_as_float(d.z & 0xffff0000u);
        r.v[6] = __uint_as_float(d.w << 16); r.v[7] = __uint_as_float(d.w & 0xffff0000u);
        return r;
    };

    auto body = [&](int2 q, F8 xv, bool active) {
        float w = __int_as_float(q.y);
        float p = 0.f;
        #pragma unroll
        for (int k = 0; k < 8; ++k) {
            float v = xv.v[k] + fmaf(w, We8[k], xr8[k]);
            float m = fmaxf(v, 0.2f * v);      // leaky_relu(0.2)
            p = fmaf(att8[k], m, p);
        }
        p = group_reduce<LPE>(p);              // per-edge score, DPP only
        float e = active ? __expf(p) : 0.f;
        wsum  += active ? w : 0.f;
        denom += e;
        #pragma unroll
        for (int k = 0; k < 8; ++k) acc[k] = fmaf(e, xv.v[k], acc[k]);
    };

    int j = start;
    for (; j + 2 * SG <= end; j += 2 * SG) {   // 2 rounds in flight
        int2 qa = slot[j + g];
        int2 qb = slot[j + SG + g];
        F8 xa = gather(qa.x);
        F8 xb = gather(qb.x);
        body(qa, xa, true);
        body(qb, xb, true);
    }
    for (; j + SG <= end; j += SG) {
        int2 q = slot[j + g];
        F8 xv = gather(q.x);
        body(q, xv, true);
    }
    if (j < end) {                             // predicated tail round
        int idx = min(j + g, end - 1);
        int2 q = slot[idx];
        F8 xv = gather(q.x);
        body(q, xv, (j + g) < end);
    }

    // combine partials across the SG subgroups (once per node)
    #pragma unroll
    for (int mask = LPE; mask < 64; mask <<= 1) {
        denom += __shfl_xor(denom, mask);
        wsum  += __shfl_xor(wsum,  mask);
        #pragma unroll
        for (int k = 0; k < 8; ++k) acc[k] += __shfl_xor(acc[k], mask);
    }

    {   // self-loop: w = mean of incoming edge weights
        float w = wsum / (float)max(end - start, 1);
        F8 xv = gather(node);
        float p = 0.f;
        #pragma unroll
        for (int k = 0; k < 8; ++k) {
            float v = xv.v[k] + fmaf(w, We8[k], xr8[k]);
            float m = fmaxf(v, 0.2f * v);
            p = fmaf(att8[k], m, p);
        }
        p = group_reduce<LPE>(p);
        float e = __expf(p);
        denom += e;
        #pragma unroll
        for (int k = 0; k < 8; ++k) acc[k] = fmaf(e, xv.v[k], acc[k]);
    }

    float res[8];
    #pragma unroll
    for (int k = 0; k < 8; ++k) res[k] = acc[k] / denom + bias8[k];
    if (ACT == 0) {                            // ELU
        #pragma unroll
        for (int k = 0; k < 8; ++k)
            res[k] = res[k] > 0.f ? res[k] : expm1f(res[k]);
    } else {                                   // softplus + 1e-4
        #pragma unroll
        for (int k = 0; k < 8; ++k)
            res[k] = fmaxf(res[k], 0.f) + log1pf(expf(-fabsf(res[k]))) + 1e-4f;
    }
    if (g == 0) {
        *(float4*)(out + (size_t)node * D + 8 * t)     = *(float4*)&res[0];
        *(float4*)(out + (size_t)node * D + 8 * t + 4) = *(float4*)&res[4];
    }
}

// ---------------------------------------------------------------------------
extern "C" void kernel_launch(void* const* d_in, const int* in_sizes, int n_in,
                              void* d_out, int out_size, void* d_ws, size_t ws_size,
                              hipStream_t stream)
{
    const float* x     = (const float*)d_in[0];
    const int*   ei    = (const int*)d_in[1];     // (2, E) int32
    const float* ew    = (const float*)d_in[2];
    const float* Wl1   = (const float*)d_in[3];
    const float* bl1   = (const float*)d_in[4];
    const float* Wr1   = (const float*)d_in[5];
    const float* br1   = (const float*)d_in[6];
    const float* We1   = (const float*)d_in[7];
    const float* att1  = (const float*)d_in[8];
    const float* bias1 = (const float*)d_in[9];
    const float* Wl2   = (const float*)d_in[10];
    const float* bl2   = (const float*)d_in[11];
    const float* Wr2   = (const float*)d_in[12];
    const float* br2   = (const float*)d_in[13];
    const float* We2   = (const float*)d_in[14];
    const float* att2  = (const float*)d_in[15];
    const float* bias2 = (const float*)d_in[16];
    float* out = (float*)d_out;

    const int n = in_sizes[0] / 128;
    const int E = in_sizes[2];
    const int NB = (n + 255) / 256;

    char* wp = (char*)d_ws;
    auto carve = [&](size_t bytes) -> void* {
        void* p = (void*)wp;
        wp += (bytes + 255) & ~(size_t)255;
        return p;
    };
    int*      cnt     = (int*)     carve((size_t)n * 4);
    int*      row_off = (int*)     carve((size_t)(n + 1) * 4);
    int*      rank    = (int*)     carve((size_t)E * 4);
    int*      bsums   = (int*)     carve((size_t)256 * 4);
    int2*     slot    = (int2*)    carve((size_t)E * 8);
    ushort_t* xl1     = (ushort_t*)carve((size_t)n * 64 * 2);
    float*    xr1     = (float*)   carve((size_t)n * 64 * 4);
    float*    hbuf    = (float*)   carve((size_t)n * 64 * 4);
    ushort_t* xl2     = (ushort_t*)carve((size_t)n * 32 * 2);
    float*    xr2     = (float*)   carve((size_t)n * 32 * 4);

    hipMemsetAsync(cnt, 0, (size_t)n * 4, stream);

    deg_kernel    <<<(E + 255) / 256, 256, 0, stream>>>(ei, cnt, rank, E);
    scan_p1       <<<NB, 256, 0, stream>>>(cnt, bsums, n);
    scan_p2       <<<1, 256, 0, stream>>>(bsums, NB);
    scan_p3       <<<NB, 256, 0, stream>>>(cnt, bsums, row_off, n);
    scatter_kernel<<<(E + 255) / 256, 256, 0, stream>>>(ei, ew, row_off, rank, slot, E);

    // layer 1
    gemm_xw<128, 128><<<(n + 127) / 128, 256, 0, stream>>>(x, Wl1, Wr1, bl1, br1, xl1, xr1, n);
    edge_attn<64, 0><<<(n + 3) / 4, 256, 0, stream>>>(xl1, xr1, We1, att1, bias1,
                                                      row_off, slot, hbuf, n);
    // layer 2
    gemm_xw<64, 64><<<(n + 127) / 128, 256, 0, stream>>>(hbuf, Wl2, Wr2, bl2, br2, xl2, xr2, n);
    edge_attn<32, 1><<<(n + 3) / 4, 256, 0, stream>>>(xl2, xr2, We2, att2, bias2,
                                                      row_off, slot, out, n);
}

// Round 8
// 295.511 us; speedup vs baseline: 1.1548x; 1.1548x over previous
//
#include <hip/hip_runtime.h>
#include <math.h>

// ---------------------------------------------------------------------------
// DPP-based add: x += x[lane ^ pattern], pure VALU.
// 0xB1 quad_perm xor1 | 0x4E quad_perm xor2 | 0x141 row_half_mirror (xor7)
// 0x140 row_mirror (xor15)
// ---------------------------------------------------------------------------
template<int CTRL>
__device__ __forceinline__ float dpp_addf(float x)
{
    int y = __builtin_amdgcn_update_dpp(0, __float_as_int(x), CTRL, 0xf, 0xf, true);
    return x + __int_as_float(y);
}

template<int LPE>
__device__ __forceinline__ float group_reduce(float p)
{
    p = dpp_addf<0xB1>(p);                           // xor 1
    p = dpp_addf<0x4E>(p);                           // xor 2
    if constexpr (LPE >= 8)  p = dpp_addf<0x141>(p); // xor 7
    if constexpr (LPE >= 16) p = dpp_addf<0x140>(p); // xor 15
    return p;
}

// ---------------------------------------------------------------------------
// Graph prep kernels
// ---------------------------------------------------------------------------

__global__ __launch_bounds__(256)
void deg_kernel(const int* __restrict__ ei, int* __restrict__ cnt,
                int* __restrict__ rank, int E)
{
    int e = blockIdx.x * 256 + threadIdx.x;
    if (e >= E) return;
    rank[e] = atomicAdd(&cnt[ei[E + e]], 1);
}

__global__ __launch_bounds__(256)
void scan_p1(const int* __restrict__ cnt, int* __restrict__ bsums, int n)
{
    __shared__ int s[256];
    const int tid = threadIdx.x;
    int gi = blockIdx.x * 256 + tid;
    s[tid] = (gi < n) ? cnt[gi] : 0;
    __syncthreads();
    #pragma unroll
    for (int off = 128; off >= 1; off >>= 1) {
        if (tid < off) s[tid] += s[tid + off];
        __syncthreads();
    }
    if (tid == 0) bsums[blockIdx.x] = s[0];
}

__global__ __launch_bounds__(256)
void scan_p2(int* __restrict__ bsums, int nb)
{
    __shared__ int s[256];
    const int tid = threadIdx.x;
    int v = (tid < nb) ? bsums[tid] : 0;
    s[tid] = v;
    __syncthreads();
    #pragma unroll
    for (int off = 1; off < 256; off <<= 1) {
        int t = (tid >= off) ? s[tid - off] : 0;
        __syncthreads();
        s[tid] += t;
        __syncthreads();
    }
    if (tid < nb) bsums[tid] = s[tid] - v;      // exclusive
}

__global__ __launch_bounds__(256)
void scan_p3(const int* __restrict__ cnt, const int* __restrict__ bsums,
             int* __restrict__ row_off, int n)
{
    __shared__ int s[256];
    const int tid = threadIdx.x;
    int gi = blockIdx.x * 256 + tid;
    int c = (gi < n) ? cnt[gi] : 0;
    s[tid] = c;
    __syncthreads();
    #pragma unroll
    for (int off = 1; off < 256; off <<= 1) {
        int t = (tid >= off) ? s[tid - off] : 0;
        __syncthreads();
        s[tid] += t;
        __syncthreads();
    }
    if (gi < n) {
        int excl = bsums[blockIdx.x] + s[tid] - c;
        row_off[gi] = excl;
        if (gi == n - 1) row_off[n] = excl + c;   // == E
    }
}

// atomic-free scatter: slot position = row_off[dst] + rank
__global__ __launch_bounds__(256)
void scatter_kernel(const int* __restrict__ ei, const float* __restrict__ ew,
                    const int* __restrict__ row_off, const int* __restrict__ rank,
                    int2* __restrict__ slot, int E)
{
    int e = blockIdx.x * 256 + threadIdx.x;
    if (e >= E) return;
    int d = ei[E + e];
    slot[row_off[d] + rank[e]] = make_int2(ei[e], __float_as_int(ew[e]));
}

// ---------------------------------------------------------------------------
// Fused linear: C[m][col] = sum_k X[m][k] * W[col][k] + bias[col]
// (XOR-quad-swizzled LDS, 128x128 tile, K chunks of 32 — proven r4 version)
// ---------------------------------------------------------------------------
template<int N, int K>
__global__ __launch_bounds__(256, 2)
void gemm_xw(const float* __restrict__ X,
             const float* __restrict__ Wa, const float* __restrict__ Wb,
             const float* __restrict__ ba, const float* __restrict__ bb,
             float* __restrict__ OutA, float* __restrict__ OutB, int M)
{
    constexpr int NJ = N / 16;
    __shared__ float sA[128 * 32];
    __shared__ float sB[N * 32];
    const int tid = threadIdx.x;
    const int m0  = blockIdx.x * 128;
    const int rg  = tid >> 4;
    const int cg  = tid & 15;

    float acc[8][NJ];
    #pragma unroll
    for (int i = 0; i < 8; ++i)
        #pragma unroll
        for (int j = 0; j < NJ; ++j) acc[i][j] = 0.f;

    const int sr = tid >> 3;
    const int kq = tid & 7;
    const int aswz = (kq ^ (sr & 7)) << 2;

    for (int kb = 0; kb < K; kb += 32) {
        #pragma unroll
        for (int p = 0; p < 4; ++p) {
            int r = sr + 32 * p;
            float4 v = make_float4(0.f, 0.f, 0.f, 0.f);
            int gr = m0 + r;
            if (gr < M) v = *(const float4*)(X + (size_t)gr * K + kb + kq * 4);
            *(float4*)&sA[r * 32 + aswz] = v;
        }
        #pragma unroll
        for (int p = 0; p < N / 32; ++p) {
            int r = sr + 32 * p;
            const float* Wsrc = (r < N / 2) ? (Wa + (size_t)r * K)
                                            : (Wb + (size_t)(r - N / 2) * K);
            float4 v = *(const float4*)(Wsrc + kb + kq * 4);
            *(float4*)&sB[r * 32 + aswz] = v;
        }
        __syncthreads();

        #pragma unroll
        for (int q = 0; q < 8; ++q) {
            float4 a4[8], b4[NJ];
            const int sa_off = (q ^ (rg & 7)) << 2;
            const int sb_off = (q ^ (cg & 7)) << 2;
            #pragma unroll
            for (int i = 0; i < 8; ++i)
                a4[i] = *(const float4*)&sA[(rg + 16 * i) * 32 + sa_off];
            #pragma unroll
            for (int j = 0; j < NJ; ++j)
                b4[j] = *(const float4*)&sB[(cg + 16 * j) * 32 + sb_off];
            #pragma unroll
            for (int i = 0; i < 8; ++i)
                #pragma unroll
                for (int j = 0; j < NJ; ++j) {
                    acc[i][j] += a4[i].x * b4[j].x;
                    acc[i][j] += a4[i].y * b4[j].y;
                    acc[i][j] += a4[i].z * b4[j].z;
                    acc[i][j] += a4[i].w * b4[j].w;
                }
        }
        __syncthreads();
    }

    #pragma unroll
    for (int i = 0; i < 8; ++i) {
        int row = m0 + rg + 16 * i;
        if (row >= M) continue;
        #pragma unroll
        for (int j = 0; j < NJ; ++j) {
            int col = cg + 16 * j;
            if (col < N / 2) {
                OutA[(size_t)row * (N / 2) + col] = acc[i][j] + ba[col];
            } else {
                OutB[(size_t)row * (N / 2) + col - N / 2] = acc[i][j] + bb[col - N / 2];
            }
        }
    }
}

// ---------------------------------------------------------------------------
// Per-node GATv2 attention + aggregation, float4-per-lane layout (r6 proven)
// + 4-deep software pipeline: q[4]/xv[4] register arrays, fully unrolled
// indices, so up to 4 gather rounds are in flight per wave to hide the
// ~300cyc L2 gather latency (r7 post-mortem: kernel is latency-chain bound,
// not VALU-issue bound).
// ACT: 0 = ELU (layer 1), 1 = softplus + 1e-4 (layer 2)
// ---------------------------------------------------------------------------
template<int D, int ACT>
__global__ __launch_bounds__(256)
void edge_attn(const float* __restrict__ xl, const float* __restrict__ xr,
               const float* __restrict__ We, const float* __restrict__ att,
               const float* __restrict__ bias,
               const int* __restrict__ row_off, const int2* __restrict__ slot,
               float* __restrict__ out, int n)
{
    constexpr int LPE = D / 4;                 // lanes per edge
    constexpr int SG  = 64 / LPE;              // edges per round
    const int lane = threadIdx.x & 63;
    const int wid  = threadIdx.x >> 6;
    const int t    = lane % LPE;               // owns dims 4t..4t+3
    const int g    = lane / LPE;               // edge slot within round
    const int node = blockIdx.x * 4 + wid;
    if (node >= n) return;

    const float4 We4   = *(const float4*)(We   + 4 * t);
    const float4 att4  = *(const float4*)(att  + 4 * t);
    const float4 bias4 = *(const float4*)(bias + 4 * t);
    const float4 xr4   = *(const float4*)(xr + (size_t)node * D + 4 * t);

    const int start = row_off[node];
    const int end   = row_off[node + 1];

    float denom = 0.f, wsum = 0.f;
    float4 acc = make_float4(0.f, 0.f, 0.f, 0.f);

    auto body = [&](int2 q, float4 xv, bool active) {
        float w = __int_as_float(q.y);
        float4 v;
        v.x = xv.x + fmaf(w, We4.x, xr4.x);
        v.y = xv.y + fmaf(w, We4.y, xr4.y);
        v.z = xv.z + fmaf(w, We4.z, xr4.z);
        v.w = xv.w + fmaf(w, We4.w, xr4.w);
        float4 m;
        m.x = fmaxf(v.x, 0.2f * v.x);
        m.y = fmaxf(v.y, 0.2f * v.y);
        m.z = fmaxf(v.z, 0.2f * v.z);
        m.w = fmaxf(v.w, 0.2f * v.w);
        float p = att4.x * m.x + att4.y * m.y + att4.z * m.z + att4.w * m.w;
        p = group_reduce<LPE>(p);              // per-edge score, DPP only
        float e = active ? __expf(p) : 0.f;
        wsum  += active ? w : 0.f;
        denom += e;
        acc.x = fmaf(e, xv.x, acc.x);
        acc.y = fmaf(e, xv.y, acc.y);
        acc.z = fmaf(e, xv.z, acc.z);
        acc.w = fmaf(e, xv.w, acc.w);
    };

    const int R = (end - start) / SG;          // full rounds
    int2   q[4];
    float4 xv[4];
    // prefetch up to 4 rounds (all loads issued back-to-back, 4 in flight)
    #pragma unroll
    for (int s = 0; s < 4; ++s) {
        if (s < R) {
            q[s]  = slot[start + s * SG + g];
            xv[s] = *(const float4*)(xl + (size_t)q[s].x * D + 4 * t);
        }
    }
    int b = 0;
    for (; b + 4 <= R; b += 4) {               // steady state
        #pragma unroll
        for (int s = 0; s < 4; ++s) {
            int2 cq = q[s]; float4 cx = xv[s];
            int nr = b + 4 + s;
            if (nr < R) {                      // refill stage s
                q[s]  = slot[start + nr * SG + g];
                xv[s] = *(const float4*)(xl + (size_t)q[s].x * D + 4 * t);
            }
            body(cq, cx, true);
        }
    }
    #pragma unroll
    for (int s = 0; s < 4; ++s)                // leftover full rounds
        if (b + s < R) body(q[s], xv[s], true);

    int j = start + R * SG;
    if (j < end) {                             // predicated tail round
        int idx = min(j + g, end - 1);
        int2 tq = slot[idx];
        float4 tx = *(const float4*)(xl + (size_t)tq.x * D + 4 * t);
        body(tq, tx, (j + g) < end);
    }

    // combine partials across the SG subgroups (once per node)
    #pragma unroll
    for (int mask = LPE; mask < 64; mask <<= 1) {
        denom += __shfl_xor(denom, mask);
        wsum  += __shfl_xor(wsum,  mask);
        acc.x += __shfl_xor(acc.x, mask);
        acc.y += __shfl_xor(acc.y, mask);
        acc.z += __shfl_xor(acc.z, mask);
        acc.w += __shfl_xor(acc.w, mask);
    }

    {   // self-loop: w = mean of incoming edge weights
        float w = wsum / (float)max(end - start, 1);
        float4 xvs = *(const float4*)(xl + (size_t)node * D + 4 * t);
        float4 v;
        v.x = xvs.x + fmaf(w, We4.x, xr4.x);
        v.y = xvs.y + fmaf(w, We4.y, xr4.y);
        v.z = xvs.z + fmaf(w, We4.z, xr4.z);
        v.w = xvs.w + fmaf(w, We4.w, xr4.w);
        float4 m;
        m.x = fmaxf(v.x, 0.2f * v.x);
        m.y = fmaxf(v.y, 0.2f * v.y);
        m.z = fmaxf(v.z, 0.2f * v.z);
        m.w = fmaxf(v.w, 0.2f * v.w);
        float p = att4.x * m.x + att4.y * m.y + att4.z * m.z + att4.w * m.w;
        p = group_reduce<LPE>(p);
        float e = __expf(p);
        denom += e;
        acc.x = fmaf(e, xvs.x, acc.x);
        acc.y = fmaf(e, xvs.y, acc.y);
        acc.z = fmaf(e, xvs.z, acc.z);
        acc.w = fmaf(e, xvs.w, acc.w);
    }

    float4 res;
    res.x = acc.x / denom + bias4.x;
    res.y = acc.y / denom + bias4.y;
    res.z = acc.z / denom + bias4.z;
    res.w = acc.w / denom + bias4.w;
    if (ACT == 0) {
        // ELU via hw exp: max(r,0) + exp(min(r,0)) - 1   (exact for r>=0)
        res.x = fmaxf(res.x, 0.f) + __expf(fminf(res.x, 0.f)) - 1.f;
        res.y = fmaxf(res.y, 0.f) + __expf(fminf(res.y, 0.f)) - 1.f;
        res.z = fmaxf(res.z, 0.f) + __expf(fminf(res.z, 0.f)) - 1.f;
        res.w = fmaxf(res.w, 0.f) + __expf(fminf(res.w, 0.f)) - 1.f;
    } else {
        // softplus via hw exp/log + 1e-4
        res.x = fmaxf(res.x, 0.f) + __logf(1.f + __expf(-fabsf(res.x))) + 1e-4f;
        res.y = fmaxf(res.y, 0.f) + __logf(1.f + __expf(-fabsf(res.y))) + 1e-4f;
        res.z = fmaxf(res.z, 0.f) + __logf(1.f + __expf(-fabsf(res.z))) + 1e-4f;
        res.w = fmaxf(res.w, 0.f) + __logf(1.f + __expf(-fabsf(res.w))) + 1e-4f;
    }
    if (g == 0)
        *(float4*)(out + (size_t)node * D + 4 * t) = res;
}

// ---------------------------------------------------------------------------
extern "C" void kernel_launch(void* const* d_in, const int* in_sizes, int n_in,
                              void* d_out, int out_size, void* d_ws, size_t ws_size,
                              hipStream_t stream)
{
    const float* x     = (const float*)d_in[0];
    const int*   ei    = (const int*)d_in[1];     // (2, E) int32
    const float* ew    = (const float*)d_in[2];
    const float* Wl1   = (const float*)d_in[3];
    const float* bl1   = (const float*)d_in[4];
    const float* Wr1   = (const float*)d_in[5];
    const float* br1   = (const float*)d_in[6];
    const float* We1   = (const float*)d_in[7];
    const float* att1  = (const float*)d_in[8];
    const float* bias1 = (const float*)d_in[9];
    const float* Wl2   = (const float*)d_in[10];
    const float* bl2   = (const float*)d_in[11];
    const float* Wr2   = (const float*)d_in[12];
    const float* br2   = (const float*)d_in[13];
    const float* We2   = (const float*)d_in[14];
    const float* att2  = (const float*)d_in[15];
    const float* bias2 = (const float*)d_in[16];
    float* out = (float*)d_out;

    const int n = in_sizes[0] / 128;
    const int E = in_sizes[2];
    const int NB = (n + 255) / 256;

    char* wp = (char*)d_ws;
    auto carve = [&](size_t bytes) -> void* {
        void* p = (void*)wp;
        wp += (bytes + 255) & ~(size_t)255;
        return p;
    };
    int*   cnt     = (int*)  carve((size_t)n * 4);
    int*   row_off = (int*)  carve((size_t)(n + 1) * 4);
    int*   rank    = (int*)  carve((size_t)E * 4);
    int*   bsums   = (int*)  carve((size_t)256 * 4);
    int2*  slot    = (int2*) carve((size_t)E * 8);
    float* xl1     = (float*)carve((size_t)n * 64 * 4);
    float* xr1     = (float*)carve((size_t)n * 64 * 4);
    float* hbuf    = (float*)carve((size_t)n * 64 * 4);
    float* xl2     = (float*)carve((size_t)n * 32 * 4);
    float* xr2     = (float*)carve((size_t)n * 32 * 4);

    hipMemsetAsync(cnt, 0, (size_t)n * 4, stream);

    deg_kernel    <<<(E + 255) / 256, 256, 0, stream>>>(ei, cnt, rank, E);
    scan_p1       <<<NB, 256, 0, stream>>>(cnt, bsums, n);
    scan_p2       <<<1, 256, 0, stream>>>(bsums, NB);
    scan_p3       <<<NB, 256, 0, stream>>>(cnt, bsums, row_off, n);
    scatter_kernel<<<(E + 255) / 256, 256, 0, stream>>>(ei, ew, row_off, rank, slot, E);

    // layer 1
    gemm_xw<128, 128><<<(n + 127) / 128, 256, 0, stream>>>(x, Wl1, Wr1, bl1, br1, xl1, xr1, n);
    edge_attn<64, 0><<<(n + 3) / 4, 256, 0, stream>>>(xl1, xr1, We1, att1, bias1,
                                                      row_off, slot, hbuf, n);
    // layer 2
    gemm_xw<64, 64><<<(n + 127) / 128, 256, 0, stream>>>(hbuf, Wl2, Wr2, bl2, br2, xl2, xr2, n);
    edge_attn<32, 1><<<(n + 3) / 4, 256, 0, stream>>>(xl2, xr2, We2, att2, bias2,
                                                      row_off, slot, out, n);
}

// Round 9
// 285.000 us; speedup vs baseline: 1.1974x; 1.0369x over previous
//
#include <hip/hip_runtime.h>
#include <math.h>

typedef unsigned short ushort_t;

// ---------------------------------------------------------------------------
// DPP-based add: x += x[lane ^ pattern], pure VALU.
// 0xB1 quad_perm xor1 | 0x4E quad_perm xor2 | 0x141 row_half_mirror (xor7)
// 0x140 row_mirror (xor15)
// ---------------------------------------------------------------------------
template<int CTRL>
__device__ __forceinline__ float dpp_addf(float x)
{
    int y = __builtin_amdgcn_update_dpp(0, __float_as_int(x), CTRL, 0xf, 0xf, true);
    return x + __int_as_float(y);
}

template<int LPE>
__device__ __forceinline__ float group_reduce(float p)
{
    p = dpp_addf<0xB1>(p);                           // xor 1
    p = dpp_addf<0x4E>(p);                           // xor 2
    if constexpr (LPE >= 8)  p = dpp_addf<0x141>(p); // xor 7
    if constexpr (LPE >= 16) p = dpp_addf<0x140>(p); // xor 15
    return p;
}

__device__ __forceinline__ ushort_t f2bf(float f)
{
    unsigned u = __float_as_uint(f);
    return (ushort_t)((u + 0x7fffu + ((u >> 16) & 1u)) >> 16);   // RNE
}

// ---------------------------------------------------------------------------
// Graph prep kernels
// ---------------------------------------------------------------------------

__global__ __launch_bounds__(256)
void deg_kernel(const int* __restrict__ ei, int* __restrict__ cnt,
                int* __restrict__ rank, int E)
{
    int e = blockIdx.x * 256 + threadIdx.x;
    if (e >= E) return;
    rank[e] = atomicAdd(&cnt[ei[E + e]], 1);
}

__global__ __launch_bounds__(256)
void scan_p1(const int* __restrict__ cnt, int* __restrict__ bsums, int n)
{
    __shared__ int s[256];
    const int tid = threadIdx.x;
    int gi = blockIdx.x * 256 + tid;
    s[tid] = (gi < n) ? cnt[gi] : 0;
    __syncthreads();
    #pragma unroll
    for (int off = 128; off >= 1; off >>= 1) {
        if (tid < off) s[tid] += s[tid + off];
        __syncthreads();
    }
    if (tid == 0) bsums[blockIdx.x] = s[0];
}

__global__ __launch_bounds__(256)
void scan_p2(int* __restrict__ bsums, int nb)
{
    __shared__ int s[256];
    const int tid = threadIdx.x;
    int v = (tid < nb) ? bsums[tid] : 0;
    s[tid] = v;
    __syncthreads();
    #pragma unroll
    for (int off = 1; off < 256; off <<= 1) {
        int t = (tid >= off) ? s[tid - off] : 0;
        __syncthreads();
        s[tid] += t;
        __syncthreads();
    }
    if (tid < nb) bsums[tid] = s[tid] - v;      // exclusive
}

__global__ __launch_bounds__(256)
void scan_p3(const int* __restrict__ cnt, const int* __restrict__ bsums,
             int* __restrict__ row_off, int n)
{
    __shared__ int s[256];
    const int tid = threadIdx.x;
    int gi = blockIdx.x * 256 + tid;
    int c = (gi < n) ? cnt[gi] : 0;
    s[tid] = c;
    __syncthreads();
    #pragma unroll
    for (int off = 1; off < 256; off <<= 1) {
        int t = (tid >= off) ? s[tid - off] : 0;
        __syncthreads();
        s[tid] += t;
        __syncthreads();
    }
    if (gi < n) {
        int excl = bsums[blockIdx.x] + s[tid] - c;
        row_off[gi] = excl;
        if (gi == n - 1) row_off[n] = excl + c;   // == E
    }
}

// atomic-free scatter: slot position = row_off[dst] + rank
__global__ __launch_bounds__(256)
void scatter_kernel(const int* __restrict__ ei, const float* __restrict__ ew,
                    const int* __restrict__ row_off, const int* __restrict__ rank,
                    int2* __restrict__ slot, int E)
{
    int e = blockIdx.x * 256 + threadIdx.x;
    if (e >= E) return;
    int d = ei[E + e];
    slot[row_off[d] + rank[e]] = make_int2(ei[e], __float_as_int(ew[e]));
}

// ---------------------------------------------------------------------------
// Fused linear: xl (cols [0,N/2)) -> bf16, xr (cols [N/2,N)) -> fp32.
// XOR-quad-swizzled LDS, 128x128 tile, K chunks of 32 (r4-proven core).
// ---------------------------------------------------------------------------
template<int N, int K>
__global__ __launch_bounds__(256, 2)
void gemm_xw(const float* __restrict__ X,
             const float* __restrict__ Wa, const float* __restrict__ Wb,
             const float* __restrict__ ba, const float* __restrict__ bb,
             ushort_t* __restrict__ OutA, float* __restrict__ OutB, int M)
{
    constexpr int NJ = N / 16;
    __shared__ float sA[128 * 32];
    __shared__ float sB[N * 32];
    const int tid = threadIdx.x;
    const int m0  = blockIdx.x * 128;
    const int rg  = tid >> 4;
    const int cg  = tid & 15;

    float acc[8][NJ];
    #pragma unroll
    for (int i = 0; i < 8; ++i)
        #pragma unroll
        for (int j = 0; j < NJ; ++j) acc[i][j] = 0.f;

    const int sr = tid >> 3;
    const int kq = tid & 7;
    const int aswz = (kq ^ (sr & 7)) << 2;

    for (int kb = 0; kb < K; kb += 32) {
        #pragma unroll
        for (int p = 0; p < 4; ++p) {
            int r = sr + 32 * p;
            float4 v = make_float4(0.f, 0.f, 0.f, 0.f);
            int gr = m0 + r;
            if (gr < M) v = *(const float4*)(X + (size_t)gr * K + kb + kq * 4);
            *(float4*)&sA[r * 32 + aswz] = v;
        }
        #pragma unroll
        for (int p = 0; p < N / 32; ++p) {
            int r = sr + 32 * p;
            const float* Wsrc = (r < N / 2) ? (Wa + (size_t)r * K)
                                            : (Wb + (size_t)(r - N / 2) * K);
            float4 v = *(const float4*)(Wsrc + kb + kq * 4);
            *(float4*)&sB[r * 32 + aswz] = v;
        }
        __syncthreads();

        #pragma unroll
        for (int q = 0; q < 8; ++q) {
            float4 a4[8], b4[NJ];
            const int sa_off = (q ^ (rg & 7)) << 2;
            const int sb_off = (q ^ (cg & 7)) << 2;
            #pragma unroll
            for (int i = 0; i < 8; ++i)
                a4[i] = *(const float4*)&sA[(rg + 16 * i) * 32 + sa_off];
            #pragma unroll
            for (int j = 0; j < NJ; ++j)
                b4[j] = *(const float4*)&sB[(cg + 16 * j) * 32 + sb_off];
            #pragma unroll
            for (int i = 0; i < 8; ++i)
                #pragma unroll
                for (int j = 0; j < NJ; ++j) {
                    acc[i][j] += a4[i].x * b4[j].x;
                    acc[i][j] += a4[i].y * b4[j].y;
                    acc[i][j] += a4[i].z * b4[j].z;
                    acc[i][j] += a4[i].w * b4[j].w;
                }
        }
        __syncthreads();
    }

    #pragma unroll
    for (int i = 0; i < 8; ++i) {
        int row = m0 + rg + 16 * i;
        if (row >= M) continue;
        #pragma unroll
        for (int j = 0; j < NJ; ++j) {
            int col = cg + 16 * j;
            if (col < N / 2) {
                OutA[(size_t)row * (N / 2) + col] = f2bf(acc[i][j] + ba[col]);
            } else {
                OutB[(size_t)row * (N / 2) + col - N / 2] = acc[i][j] + bb[col - N / 2];
            }
        }
    }
}

// ---------------------------------------------------------------------------
// Per-node GATv2 attention + aggregation.
// r8 structure (LPE=D/4 lanes/edge, 4-deep SW pipeline, DPP reduce) with
// xl stored bf16: lane owns the SAME 4 dims but loads 8 B (uint2) + 4-op
// unpack. D=64 row = 128 B = ONE cacheline, array 6.4 MB -> mostly
// L2-resident (r8 profile: fp32 gather forced every XCD to stream the whole
// 12.8 MB array from HBM, FETCH=90 MB).
// ACT: 0 = ELU (layer 1), 1 = softplus + 1e-4 (layer 2)
// ---------------------------------------------------------------------------
template<int D, int ACT>
__global__ __launch_bounds__(256)
void edge_attn(const ushort_t* __restrict__ xl, const float* __restrict__ xr,
               const float* __restrict__ We, const float* __restrict__ att,
               const float* __restrict__ bias,
               const int* __restrict__ row_off, const int2* __restrict__ slot,
               float* __restrict__ out, int n)
{
    constexpr int LPE = D / 4;                 // lanes per edge
    constexpr int SG  = 64 / LPE;              // edges per round
    const int lane = threadIdx.x & 63;
    const int wid  = threadIdx.x >> 6;
    const int t    = lane % LPE;               // owns dims 4t..4t+3
    const int g    = lane / LPE;               // edge slot within round
    const int node = blockIdx.x * 4 + wid;
    if (node >= n) return;

    const float4 We4   = *(const float4*)(We   + 4 * t);
    const float4 att4  = *(const float4*)(att  + 4 * t);
    const float4 bias4 = *(const float4*)(bias + 4 * t);
    const float4 xr4   = *(const float4*)(xr + (size_t)node * D + 4 * t);

    const int start = row_off[node];
    const int end   = row_off[node + 1];

    float denom = 0.f, wsum = 0.f;
    float4 acc = make_float4(0.f, 0.f, 0.f, 0.f);

    auto unpack = [](uint2 d) -> float4 {
        float4 r;
        r.x = __uint_as_float(d.x << 16);
        r.y = __uint_as_float(d.x & 0xffff0000u);
        r.z = __uint_as_float(d.y << 16);
        r.w = __uint_as_float(d.y & 0xffff0000u);
        return r;
    };

    auto body = [&](int2 q, float4 xv, bool active) {
        float w = __int_as_float(q.y);
        float4 v;
        v.x = xv.x + fmaf(w, We4.x, xr4.x);
        v.y = xv.y + fmaf(w, We4.y, xr4.y);
        v.z = xv.z + fmaf(w, We4.z, xr4.z);
        v.w = xv.w + fmaf(w, We4.w, xr4.w);
        float4 m;
        m.x = fmaxf(v.x, 0.2f * v.x);
        m.y = fmaxf(v.y, 0.2f * v.y);
        m.z = fmaxf(v.z, 0.2f * v.z);
        m.w = fmaxf(v.w, 0.2f * v.w);
        float p = att4.x * m.x + att4.y * m.y + att4.z * m.z + att4.w * m.w;
        p = group_reduce<LPE>(p);              // per-edge score, DPP only
        float e = active ? __expf(p) : 0.f;
        wsum  += active ? w : 0.f;
        denom += e;
        acc.x = fmaf(e, xv.x, acc.x);
        acc.y = fmaf(e, xv.y, acc.y);
        acc.z = fmaf(e, xv.z, acc.z);
        acc.w = fmaf(e, xv.w, acc.w);
    };

    const int R = (end - start) / SG;          // full rounds
    int2  q[4];
    uint2 xv[4];
    #pragma unroll
    for (int s = 0; s < 4; ++s) {              // prefetch: 4 rounds in flight
        if (s < R) {
            q[s]  = slot[start + s * SG + g];
            xv[s] = *(const uint2*)(xl + (size_t)q[s].x * D + 4 * t);
        }
    }
    int b = 0;
    for (; b + 4 <= R; b += 4) {               // steady state
        #pragma unroll
        for (int s = 0; s < 4; ++s) {
            int2 cq = q[s]; uint2 cx = xv[s];
            int nr = b + 4 + s;
            if (nr < R) {                      // refill stage s
                q[s]  = slot[start + nr * SG + g];
                xv[s] = *(const uint2*)(xl + (size_t)q[s].x * D + 4 * t);
            }
            body(cq, unpack(cx), true);
        }
    }
    #pragma unroll
    for (int s = 0; s < 4; ++s)                // leftover full rounds
        if (b + s < R) body(q[s], unpack(xv[s]), true);

    int j = start + R * SG;
    if (j < end) {                             // predicated tail round
        int idx = min(j + g, end - 1);
        int2 tq = slot[idx];
        uint2 tx = *(const uint2*)(xl + (size_t)tq.x * D + 4 * t);
        body(tq, unpack(tx), (j + g) < end);
    }

    // combine partials across the SG subgroups (once per node)
    #pragma unroll
    for (int mask = LPE; mask < 64; mask <<= 1) {
        denom += __shfl_xor(denom, mask);
        wsum  += __shfl_xor(wsum,  mask);
        acc.x += __shfl_xor(acc.x, mask);
        acc.y += __shfl_xor(acc.y, mask);
        acc.z += __shfl_xor(acc.z, mask);
        acc.w += __shfl_xor(acc.w, mask);
    }

    {   // self-loop: w = mean of incoming edge weights
        float w = wsum / (float)max(end - start, 1);
        float4 xvs = unpack(*(const uint2*)(xl + (size_t)node * D + 4 * t));
        float4 v;
        v.x = xvs.x + fmaf(w, We4.x, xr4.x);
        v.y = xvs.y + fmaf(w, We4.y, xr4.y);
        v.z = xvs.z + fmaf(w, We4.z, xr4.z);
        v.w = xvs.w + fmaf(w, We4.w, xr4.w);
        float4 m;
        m.x = fmaxf(v.x, 0.2f * v.x);
        m.y = fmaxf(v.y, 0.2f * v.y);
        m.z = fmaxf(v.z, 0.2f * v.z);
        m.w = fmaxf(v.w, 0.2f * v.w);
        float p = att4.x * m.x + att4.y * m.y + att4.z * m.z + att4.w * m.w;
        p = group_reduce<LPE>(p);
        float e = __expf(p);
        denom += e;
        acc.x = fmaf(e, xvs.x, acc.x);
        acc.y = fmaf(e, xvs.y, acc.y);
        acc.z = fmaf(e, xvs.z, acc.z);
        acc.w = fmaf(e, xvs.w, acc.w);
    }

    float4 res;
    res.x = acc.x / denom + bias4.x;
    res.y = acc.y / denom + bias4.y;
    res.z = acc.z / denom + bias4.z;
    res.w = acc.w / denom + bias4.w;
    if (ACT == 0) {
        // ELU via hw exp: max(r,0) + exp(min(r,0)) - 1   (exact for r>=0)
        res.x = fmaxf(res.x, 0.f) + __expf(fminf(res.x, 0.f)) - 1.f;
        res.y = fmaxf(res.y, 0.f) + __expf(fminf(res.y, 0.f)) - 1.f;
        res.z = fmaxf(res.z, 0.f) + __expf(fminf(res.z, 0.f)) - 1.f;
        res.w = fmaxf(res.w, 0.f) + __expf(fminf(res.w, 0.f)) - 1.f;
    } else {
        // softplus via hw exp/log + 1e-4
        res.x = fmaxf(res.x, 0.f) + __logf(1.f + __expf(-fabsf(res.x))) + 1e-4f;
        res.y = fmaxf(res.y, 0.f) + __logf(1.f + __expf(-fabsf(res.y))) + 1e-4f;
        res.z = fmaxf(res.z, 0.f) + __logf(1.f + __expf(-fabsf(res.z))) + 1e-4f;
        res.w = fmaxf(res.w, 0.f) + __logf(1.f + __expf(-fabsf(res.w))) + 1e-4f;
    }
    if (g == 0)
        *(float4*)(out + (size_t)node * D + 4 * t) = res;
}

// ---------------------------------------------------------------------------
extern "C" void kernel_launch(void* const* d_in, const int* in_sizes, int n_in,
                              void* d_out, int out_size, void* d_ws, size_t ws_size,
                              hipStream_t stream)
{
    const float* x     = (const float*)d_in[0];
    const int*   ei    = (const int*)d_in[1];     // (2, E) int32
    const float* ew    = (const float*)d_in[2];
    const float* Wl1   = (const float*)d_in[3];
    const float* bl1   = (const float*)d_in[4];
    const float* Wr1   = (const float*)d_in[5];
    const float* br1   = (const float*)d_in[6];
    const float* We1   = (const float*)d_in[7];
    const float* att1  = (const float*)d_in[8];
    const float* bias1 = (const float*)d_in[9];
    const float* Wl2   = (const float*)d_in[10];
    const float* bl2   = (const float*)d_in[11];
    const float* Wr2   = (const float*)d_in[12];
    const float* br2   = (const float*)d_in[13];
    const float* We2   = (const float*)d_in[14];
    const float* att2  = (const float*)d_in[15];
    const float* bias2 = (const float*)d_in[16];
    float* out = (float*)d_out;

    const int n = in_sizes[0] / 128;
    const int E = in_sizes[2];
    const int NB = (n + 255) / 256;

    char* wp = (char*)d_ws;
    auto carve = [&](size_t bytes) -> void* {
        void* p = (void*)wp;
        wp += (bytes + 255) & ~(size_t)255;
        return p;
    };
    int*      cnt     = (int*)     carve((size_t)n * 4);
    int*      row_off = (int*)     carve((size_t)(n + 1) * 4);
    int*      rank    = (int*)     carve((size_t)E * 4);
    int*      bsums   = (int*)     carve((size_t)256 * 4);
    int2*     slot    = (int2*)    carve((size_t)E * 8);
    ushort_t* xl1     = (ushort_t*)carve((size_t)n * 64 * 2);
    float*    xr1     = (float*)   carve((size_t)n * 64 * 4);
    float*    hbuf    = (float*)   carve((size_t)n * 64 * 4);
    ushort_t* xl2     = (ushort_t*)carve((size_t)n * 32 * 2);
    float*    xr2     = (float*)   carve((size_t)n * 32 * 4);

    hipMemsetAsync(cnt, 0, (size_t)n * 4, stream);

    deg_kernel    <<<(E + 255) / 256, 256, 0, stream>>>(ei, cnt, rank, E);
    scan_p1       <<<NB, 256, 0, stream>>>(cnt, bsums, n);
    scan_p2       <<<1, 256, 0, stream>>>(bsums, NB);
    scan_p3       <<<NB, 256, 0, stream>>>(cnt, bsums, row_off, n);
    scatter_kernel<<<(E + 255) / 256, 256, 0, stream>>>(ei, ew, row_off, rank, slot, E);

    // layer 1
    gemm_xw<128, 128><<<(n + 127) / 128, 256, 0, stream>>>(x, Wl1, Wr1, bl1, br1, xl1, xr1, n);
    edge_attn<64, 0><<<(n + 3) / 4, 256, 0, stream>>>(xl1, xr1, We1, att1, bias1,
                                                      row_off, slot, hbuf, n);
    // layer 2
    gemm_xw<64, 64><<<(n + 127) / 128, 256, 0, stream>>>(hbuf, Wl2, Wr2, bl2, br2, xl2, xr2, n);
    edge_attn<32, 1><<<(n + 3) / 4, 256, 0, stream>>>(xl2, xr2, We2, att2, bias2,
                                                      row_off, slot, out, n);
}

// Round 10
// 266.914 us; speedup vs baseline: 1.2785x; 1.0678x over previous
//
#include <hip/hip_runtime.h>
#include <math.h>

typedef unsigned short ushort_t;
typedef __attribute__((ext_vector_type(8))) short bf16x8;   // MFMA A/B frag (4 VGPR)
typedef __attribute__((ext_vector_type(4))) float f32x4;    // MFMA C/D frag

// ---------------------------------------------------------------------------
// DPP-based add: x += x[lane ^ pattern], pure VALU.
// ---------------------------------------------------------------------------
template<int CTRL>
__device__ __forceinline__ float dpp_addf(float x)
{
    int y = __builtin_amdgcn_update_dpp(0, __float_as_int(x), CTRL, 0xf, 0xf, true);
    return x + __int_as_float(y);
}

template<int LPE>
__device__ __forceinline__ float group_reduce(float p)
{
    p = dpp_addf<0xB1>(p);                           // xor 1
    p = dpp_addf<0x4E>(p);                           // xor 2
    if constexpr (LPE >= 8)  p = dpp_addf<0x141>(p); // xor 7
    if constexpr (LPE >= 16) p = dpp_addf<0x140>(p); // xor 15
    return p;
}

__device__ __forceinline__ ushort_t f2bf(float f)
{
    unsigned u = __float_as_uint(f);
    return (ushort_t)((u + 0x7fffu + ((u >> 16) & 1u)) >> 16);   // RNE
}

// ---------------------------------------------------------------------------
// Graph prep kernels (unchanged, r6-proven)
// ---------------------------------------------------------------------------

__global__ __launch_bounds__(256)
void deg_kernel(const int* __restrict__ ei, int* __restrict__ cnt,
                int* __restrict__ rank, int E)
{
    int e = blockIdx.x * 256 + threadIdx.x;
    if (e >= E) return;
    rank[e] = atomicAdd(&cnt[ei[E + e]], 1);
}

__global__ __launch_bounds__(256)
void scan_p1(const int* __restrict__ cnt, int* __restrict__ bsums, int n)
{
    __shared__ int s[256];
    const int tid = threadIdx.x;
    int gi = blockIdx.x * 256 + tid;
    s[tid] = (gi < n) ? cnt[gi] : 0;
    __syncthreads();
    #pragma unroll
    for (int off = 128; off >= 1; off >>= 1) {
        if (tid < off) s[tid] += s[tid + off];
        __syncthreads();
    }
    if (tid == 0) bsums[blockIdx.x] = s[0];
}

__global__ __launch_bounds__(256)
void scan_p2(int* __restrict__ bsums, int nb)
{
    __shared__ int s[256];
    const int tid = threadIdx.x;
    int v = (tid < nb) ? bsums[tid] : 0;
    s[tid] = v;
    __syncthreads();
    #pragma unroll
    for (int off = 1; off < 256; off <<= 1) {
        int t = (tid >= off) ? s[tid - off] : 0;
        __syncthreads();
        s[tid] += t;
        __syncthreads();
    }
    if (tid < nb) bsums[tid] = s[tid] - v;      // exclusive
}

__global__ __launch_bounds__(256)
void scan_p3(const int* __restrict__ cnt, const int* __restrict__ bsums,
             int* __restrict__ row_off, int n)
{
    __shared__ int s[256];
    const int tid = threadIdx.x;
    int gi = blockIdx.x * 256 + tid;
    int c = (gi < n) ? cnt[gi] : 0;
    s[tid] = c;
    __syncthreads();
    #pragma unroll
    for (int off = 1; off < 256; off <<= 1) {
        int t = (tid >= off) ? s[tid - off] : 0;
        __syncthreads();
        s[tid] += t;
        __syncthreads();
    }
    if (gi < n) {
        int excl = bsums[blockIdx.x] + s[tid] - c;
        row_off[gi] = excl;
        if (gi == n - 1) row_off[n] = excl + c;   // == E
    }
}

__global__ __launch_bounds__(256)
void scatter_kernel(const int* __restrict__ ei, const float* __restrict__ ew,
                    const int* __restrict__ row_off, const int* __restrict__ rank,
                    int2* __restrict__ slot, int E)
{
    int e = blockIdx.x * 256 + threadIdx.x;
    if (e >= E) return;
    int d = ei[E + e];
    slot[row_off[d] + rank[e]] = make_int2(ei[e], __float_as_int(ew[e]));
}

// ---------------------------------------------------------------------------
// MFMA fused linear: C[m][col] = sum_k X[m][k]*W[col][k] + bias[col], bf16 out.
// col < N/2 -> (Wa,ba) -> OutA ; else (Wb,bb) -> OutB (both bf16).
// Block = 256 thr (4 waves), 64 rows x N cols; X-tile + full W staged in LDS
// as bf16 with +8 elem row pad (2-way bank alias only = free).
// Layouts (HW-verified m89/m91/m120): A/B frag [m|n=lane&15][k=quad*8+j];
// C/D: col=lane&15, row=quad*4+reg.
// ---------------------------------------------------------------------------
template<int N, int K>
__global__ __launch_bounds__(256, 2)
void gemm_xw_mfma(const float* __restrict__ X,
                  const float* __restrict__ Wa, const float* __restrict__ Wb,
                  const float* __restrict__ ba, const float* __restrict__ bb,
                  ushort_t* __restrict__ OutA, ushort_t* __restrict__ OutB, int M)
{
    constexpr int KP = K + 8;                   // padded row (bf16 elems)
    constexpr int KC = K / 32;                  // MFMA K-chains
    constexpr int NT = N / 16;                  // 16-col tiles
    __shared__ ushort_t sW[N * KP];
    __shared__ ushort_t sX[64 * KP];
    const int tid = threadIdx.x;
    const int m0  = blockIdx.x * 64;

    // stage W -> bf16 LDS (whole weight, both halves)
    constexpr int WQ = N * (K / 4);
    for (int q = tid; q < WQ; q += 256) {
        int nrow = q / (K / 4);
        int k4   = (q % (K / 4)) * 4;
        const float* src = (nrow < N / 2) ? Wa + (size_t)nrow * K + k4
                                          : Wb + (size_t)(nrow - N / 2) * K + k4;
        float4 v = *(const float4*)src;
        short4 h = make_short4((short)f2bf(v.x), (short)f2bf(v.y),
                               (short)f2bf(v.z), (short)f2bf(v.w));
        *(short4*)&sW[nrow * KP + k4] = h;
    }
    // stage X tile -> bf16 LDS (zero-pad past M)
    constexpr int XQ = 64 * (K / 4);
    for (int q = tid; q < XQ; q += 256) {
        int r  = q / (K / 4);
        int k4 = (q % (K / 4)) * 4;
        float4 v = make_float4(0.f, 0.f, 0.f, 0.f);
        int gr = m0 + r;
        if (gr < M) v = *(const float4*)(X + (size_t)gr * K + k4);
        short4 h = make_short4((short)f2bf(v.x), (short)f2bf(v.y),
                               (short)f2bf(v.z), (short)f2bf(v.w));
        *(short4*)&sX[r * KP + k4] = h;
    }
    __syncthreads();

    const int wv   = tid >> 6;                  // wave -> rows wv*16..+15
    const int lane = tid & 63;
    const int mrow = lane & 15;
    const int quad = lane >> 4;

    bf16x8 a[KC];
    #pragma unroll
    for (int kc = 0; kc < KC; ++kc)
        a[kc] = *(const bf16x8*)&sX[(wv * 16 + mrow) * KP + kc * 32 + quad * 8];

    #pragma unroll
    for (int nt = 0; nt < NT; ++nt) {
        f32x4 acc = {0.f, 0.f, 0.f, 0.f};
        #pragma unroll
        for (int kc = 0; kc < KC; ++kc) {
            bf16x8 b = *(const bf16x8*)&sW[(nt * 16 + mrow) * KP + kc * 32 + quad * 8];
            acc = __builtin_amdgcn_mfma_f32_16x16x32_bf16(a[kc], b, acc, 0, 0, 0);
        }
        const int col = nt * 16 + mrow;
        ushort_t* dst;
        int cc;
        float bv;
        if (col < N / 2) { dst = OutA; cc = col;         bv = ba[cc]; }
        else             { dst = OutB; cc = col - N / 2; bv = bb[cc]; }
        #pragma unroll
        for (int r = 0; r < 4; ++r) {
            int row = m0 + wv * 16 + quad * 4 + r;
            if (row < M)
                dst[(size_t)row * (N / 2) + cc] = f2bf(acc[r] + bv);
        }
    }
}

// ---------------------------------------------------------------------------
// Per-node GATv2 attention + aggregation (r9 structure: LPE=D/4 lanes/edge,
// 4-deep SW pipeline, DPP score reduce). xl AND xr now bf16 (8 B/lane loads).
// ACT: 0 = ELU (layer 1), 1 = softplus + 1e-4 (layer 2)
// ---------------------------------------------------------------------------
template<int D, int ACT>
__global__ __launch_bounds__(256)
void edge_attn(const ushort_t* __restrict__ xl, const ushort_t* __restrict__ xr,
               const float* __restrict__ We, const float* __restrict__ att,
               const float* __restrict__ bias,
               const int* __restrict__ row_off, const int2* __restrict__ slot,
               float* __restrict__ out, int n)
{
    constexpr int LPE = D / 4;                 // lanes per edge
    constexpr int SG  = 64 / LPE;              // edges per round
    const int lane = threadIdx.x & 63;
    const int wid  = threadIdx.x >> 6;
    const int t    = lane % LPE;               // owns dims 4t..4t+3
    const int g    = lane / LPE;               // edge slot within round
    const int node = blockIdx.x * 4 + wid;
    if (node >= n) return;

    auto unpack = [](uint2 d) -> float4 {
        float4 r;
        r.x = __uint_as_float(d.x << 16);
        r.y = __uint_as_float(d.x & 0xffff0000u);
        r.z = __uint_as_float(d.y << 16);
        r.w = __uint_as_float(d.y & 0xffff0000u);
        return r;
    };

    const float4 We4   = *(const float4*)(We   + 4 * t);
    const float4 att4  = *(const float4*)(att  + 4 * t);
    const float4 bias4 = *(const float4*)(bias + 4 * t);
    const float4 xr4   = unpack(*(const uint2*)(xr + (size_t)node * D + 4 * t));

    const int start = row_off[node];
    const int end   = row_off[node + 1];

    float denom = 0.f, wsum = 0.f;
    float4 acc = make_float4(0.f, 0.f, 0.f, 0.f);

    auto body = [&](int2 q, float4 xv, bool active) {
        float w = __int_as_float(q.y);
        float4 v;
        v.x = xv.x + fmaf(w, We4.x, xr4.x);
        v.y = xv.y + fmaf(w, We4.y, xr4.y);
        v.z = xv.z + fmaf(w, We4.z, xr4.z);
        v.w = xv.w + fmaf(w, We4.w, xr4.w);
        float4 m;
        m.x = fmaxf(v.x, 0.2f * v.x);
        m.y = fmaxf(v.y, 0.2f * v.y);
        m.z = fmaxf(v.z, 0.2f * v.z);
        m.w = fmaxf(v.w, 0.2f * v.w);
        float p = att4.x * m.x + att4.y * m.y + att4.z * m.z + att4.w * m.w;
        p = group_reduce<LPE>(p);              // per-edge score, DPP only
        float e = active ? __expf(p) : 0.f;
        wsum  += active ? w : 0.f;
        denom += e;
        acc.x = fmaf(e, xv.x, acc.x);
        acc.y = fmaf(e, xv.y, acc.y);
        acc.z = fmaf(e, xv.z, acc.z);
        acc.w = fmaf(e, xv.w, acc.w);
    };

    const int R = (end - start) / SG;          // full rounds
    int2  q[4];
    uint2 xv[4];
    #pragma unroll
    for (int s = 0; s < 4; ++s) {              // prefetch: 4 rounds in flight
        if (s < R) {
            q[s]  = slot[start + s * SG + g];
            xv[s] = *(const uint2*)(xl + (size_t)q[s].x * D + 4 * t);
        }
    }
    int b = 0;
    for (; b + 4 <= R; b += 4) {               // steady state
        #pragma unroll
        for (int s = 0; s < 4; ++s) {
            int2 cq = q[s]; uint2 cx = xv[s];
            int nr = b + 4 + s;
            if (nr < R) {                      // refill stage s
                q[s]  = slot[start + nr * SG + g];
                xv[s] = *(const uint2*)(xl + (size_t)q[s].x * D + 4 * t);
            }
            body(cq, unpack(cx), true);
        }
    }
    #pragma unroll
    for (int s = 0; s < 4; ++s)                // leftover full rounds
        if (b + s < R) body(q[s], unpack(xv[s]), true);

    int j = start + R * SG;
    if (j < end) {                             // predicated tail round
        int idx = min(j + g, end - 1);
        int2 tq = slot[idx];
        uint2 tx = *(const uint2*)(xl + (size_t)tq.x * D + 4 * t);
        body(tq, unpack(tx), (j + g) < end);
    }

    // combine partials across the SG subgroups (once per node)
    #pragma unroll
    for (int mask = LPE; mask < 64; mask <<= 1) {
        denom += __shfl_xor(denom, mask);
        wsum  += __shfl_xor(wsum,  mask);
        acc.x += __shfl_xor(acc.x, mask);
        acc.y += __shfl_xor(acc.y, mask);
        acc.z += __shfl_xor(acc.z, mask);
        acc.w += __shfl_xor(acc.w, mask);
    }

    {   // self-loop: w = mean of incoming edge weights
        float w = wsum / (float)max(end - start, 1);
        float4 xvs = unpack(*(const uint2*)(xl + (size_t)node * D + 4 * t));
        float4 v;
        v.x = xvs.x + fmaf(w, We4.x, xr4.x);
        v.y = xvs.y + fmaf(w, We4.y, xr4.y);
        v.z = xvs.z + fmaf(w, We4.z, xr4.z);
        v.w = xvs.w + fmaf(w, We4.w, xr4.w);
        float4 m;
        m.x = fmaxf(v.x, 0.2f * v.x);
        m.y = fmaxf(v.y, 0.2f * v.y);
        m.z = fmaxf(v.z, 0.2f * v.z);
        m.w = fmaxf(v.w, 0.2f * v.w);
        float p = att4.x * m.x + att4.y * m.y + att4.z * m.z + att4.w * m.w;
        p = group_reduce<LPE>(p);
        float e = __expf(p);
        denom += e;
        acc.x = fmaf(e, xvs.x, acc.x);
        acc.y = fmaf(e, xvs.y, acc.y);
        acc.z = fmaf(e, xvs.z, acc.z);
        acc.w = fmaf(e, xvs.w, acc.w);
    }

    float4 res;
    res.x = acc.x / denom + bias4.x;
    res.y = acc.y / denom + bias4.y;
    res.z = acc.z / denom + bias4.z;
    res.w = acc.w / denom + bias4.w;
    if (ACT == 0) {
        // ELU via hw exp: max(r,0) + exp(min(r,0)) - 1   (exact for r>=0)
        res.x = fmaxf(res.x, 0.f) + __expf(fminf(res.x, 0.f)) - 1.f;
        res.y = fmaxf(res.y, 0.f) + __expf(fminf(res.y, 0.f)) - 1.f;
        res.z = fmaxf(res.z, 0.f) + __expf(fminf(res.z, 0.f)) - 1.f;
        res.w = fmaxf(res.w, 0.f) + __expf(fminf(res.w, 0.f)) - 1.f;
    } else {
        // softplus via hw exp/log + 1e-4
        res.x = fmaxf(res.x, 0.f) + __logf(1.f + __expf(-fabsf(res.x))) + 1e-4f;
        res.y = fmaxf(res.y, 0.f) + __logf(1.f + __expf(-fabsf(res.y))) + 1e-4f;
        res.z = fmaxf(res.z, 0.f) + __logf(1.f + __expf(-fabsf(res.z))) + 1e-4f;
        res.w = fmaxf(res.w, 0.f) + __logf(1.f + __expf(-fabsf(res.w))) + 1e-4f;
    }
    if (g == 0)
        *(float4*)(out + (size_t)node * D + 4 * t) = res;
}

// ---------------------------------------------------------------------------
extern "C" void kernel_launch(void* const* d_in, const int* in_sizes, int n_in,
                              void* d_out, int out_size, void* d_ws, size_t ws_size,
                              hipStream_t stream)
{
    const float* x     = (const float*)d_in[0];
    const int*   ei    = (const int*)d_in[1];     // (2, E) int32
    const float* ew    = (const float*)d_in[2];
    const float* Wl1   = (const float*)d_in[3];
    const float* bl1   = (const float*)d_in[4];
    const float* Wr1   = (const float*)d_in[5];
    const float* br1   = (const float*)d_in[6];
    const float* We1   = (const float*)d_in[7];
    const float* att1  = (const float*)d_in[8];
    const float* bias1 = (const float*)d_in[9];
    const float* Wl2   = (const float*)d_in[10];
    const float* bl2   = (const float*)d_in[11];
    const float* Wr2   = (const float*)d_in[12];
    const float* br2   = (const float*)d_in[13];
    const float* We2   = (const float*)d_in[14];
    const float* att2  = (const float*)d_in[15];
    const float* bias2 = (const float*)d_in[16];
    float* out = (float*)d_out;

    const int n = in_sizes[0] / 128;
    const int E = in_sizes[2];
    const int NB = (n + 255) / 256;

    char* wp = (char*)d_ws;
    auto carve = [&](size_t bytes) -> void* {
        void* p = (void*)wp;
        wp += (bytes + 255) & ~(size_t)255;
        return p;
    };
    int*      cnt     = (int*)     carve((size_t)n * 4);
    int*      row_off = (int*)     carve((size_t)(n + 1) * 4);
    int*      rank    = (int*)     carve((size_t)E * 4);
    int*      bsums   = (int*)     carve((size_t)256 * 4);
    int2*     slot    = (int2*)    carve((size_t)E * 8);
    ushort_t* xl1     = (ushort_t*)carve((size_t)n * 64 * 2);
    ushort_t* xr1     = (ushort_t*)carve((size_t)n * 64 * 2);
    float*    hbuf    = (float*)   carve((size_t)n * 64 * 4);
    ushort_t* xl2     = (ushort_t*)carve((size_t)n * 32 * 2);
    ushort_t* xr2     = (ushort_t*)carve((size_t)n * 32 * 2);

    hipMemsetAsync(cnt, 0, (size_t)n * 4, stream);

    deg_kernel    <<<(E + 255) / 256, 256, 0, stream>>>(ei, cnt, rank, E);
    scan_p1       <<<NB, 256, 0, stream>>>(cnt, bsums, n);
    scan_p2       <<<1, 256, 0, stream>>>(bsums, NB);
    scan_p3       <<<NB, 256, 0, stream>>>(cnt, bsums, row_off, n);
    scatter_kernel<<<(E + 255) / 256, 256, 0, stream>>>(ei, ew, row_off, rank, slot, E);

    // layer 1
    gemm_xw_mfma<128, 128><<<(n + 63) / 64, 256, 0, stream>>>(x, Wl1, Wr1, bl1, br1,
                                                              xl1, xr1, n);
    edge_attn<64, 0><<<(n + 3) / 4, 256, 0, stream>>>(xl1, xr1, We1, att1, bias1,
                                                      row_off, slot, hbuf, n);
    // layer 2
    gemm_xw_mfma<64, 64><<<(n + 63) / 64, 256, 0, stream>>>(hbuf, Wl2, Wr2, bl2, br2,
                                                            xl2, xr2, n);
    edge_attn<32, 1><<<(n + 3) / 4, 256, 0, stream>>>(xl2, xr2, We2, att2, bias2,
                                                      row_off, slot, out, n);
}